// Round 14
// baseline (233.833 us; speedup 1.0000x reference)
//
#include <hip/hip_runtime.h>

#define SEQ 2048
#define HID 2048
#define NH  32
#define NKV 8
#define HD  64

typedef _Float16 f16;
typedef __attribute__((ext_vector_type(4))) _Float16 f16x4;
typedef __attribute__((ext_vector_type(8))) _Float16 f16x8;
typedef __attribute__((ext_vector_type(2))) __fp16   h16x2;
typedef __attribute__((ext_vector_type(4))) float    f32x4;

__device__ __forceinline__ f32x4 mfma_16x16x32(f16x8 a, f16x8 b, f32x4 c) {
    return __builtin_amdgcn_mfma_f32_16x16x32_f16(a, b, c, 0, 0, 0);
}

// async global->LDS, 16B per lane. Global address is PER-LANE (gather);
// LDS dest is wave-uniform base + lane*16 (contiguous).
__device__ __forceinline__ void async16(const void* g, void* l) {
    __builtin_amdgcn_global_load_lds(
        (const __attribute__((address_space(1))) void*)g,
        (__attribute__((address_space(3))) void*)l,
        16, 0, 0);
}

// ---------------- prep: 4 weight transposes + x cvt in ONE launch ----------------
__global__ void prep_all(const float* __restrict__ x,
                         const float* __restrict__ wq, const float* __restrict__ wk,
                         const float* __restrict__ wv, const float* __restrict__ wo,
                         f16* __restrict__ xb,
                         f16* __restrict__ Wcat, f16* __restrict__ woT) {
    __shared__ float tile[32][33];
    int z = blockIdx.z;
    int tx = threadIdx.x, ty = threadIdx.y;
    if (z == 4) {   // cvt: 2048*2048 flat
        int idx = (blockIdx.y * 64 + blockIdx.x) * 256 + ty * 32 + tx;
        int i = idx * 4;
        float4 v = *(const float4*)(x + i);
        f16x4 o = { (f16)v.x, (f16)v.y, (f16)v.z, (f16)v.w };
        *(f16x4*)(xb + i) = o;
        return;
    }
    const float* src; f16* dst; int C;
    if      (z == 0) { src = wq; dst = Wcat;                         C = 2048; }
    else if (z == 1) { src = wk; dst = Wcat + (size_t)2048 * 2048;   C = 512;  }
    else if (z == 2) { src = wv; dst = Wcat + (size_t)2560 * 2048;   C = 512;  }
    else             { src = wo; dst = woT;                          C = 2048; }
    int c0 = blockIdx.x * 32, r0 = blockIdx.y * 32;
    if (c0 >= C) return;
#pragma unroll
    for (int i = 0; i < 32; i += 8)
        tile[ty + i][tx] = src[(size_t)(r0 + ty + i) * C + c0 + tx];
    __syncthreads();
#pragma unroll
    for (int i = 0; i < 32; i += 8)
        dst[(size_t)(c0 + ty + i) * 2048 + r0 + tx] = (f16)tile[tx][ty + i];
}

// ---------------- GEMM: C[M,N] = A[M,K] @ BT[N,K]^T ----------------
// 64(M) x 128(N) tile, BK=64 (32 barriers), 4 waves 2x2, dbuf staging with
// XOR-swizzled k-chunks (conflict-free b128 reads).
// MODE 0: A via async16; fused QKV epilogue + RoPE; V^T scaled by em[s].
// MODE 1: A staged via VGPR from attention partials: A = (O0+O1) * 1/(l0+l1),
//         head h = k-tile index (HD==BK). fp32 out. Combine kernel fused away.
template <int MODE>
__global__ __launch_bounds__(256)
void gemm_bt(const f16* __restrict__ A, const f16* __restrict__ BT,
             float* __restrict__ Cf, f16* __restrict__ Q, f16* __restrict__ Kk,
             f16* __restrict__ VT, const int* __restrict__ pos,
             const float* __restrict__ mask, const float* __restrict__ Lp,
             int N, int K) {
    __shared__ f16 As[2][64 * 64];    // [row][k-chunk swizzled]
    __shared__ f16 Bs[2][128 * 64];
    int t = threadIdx.x;
    int w = t >> 6, lane = t & 63, quad = lane >> 4, l15 = lane & 15;
    int wm = w >> 1, wn = w & 1;
    int m0 = blockIdx.y * 64, n0 = blockIdx.x * 128;
    int sw = l15 & 7;

    int r8 = lane >> 3;            // row within 8-row staging group
    int cc = (lane & 7) ^ r8;      // XOR-swizzled global k-chunk
    const f16* Ag0 = A  + (size_t)(m0 + w * 16 + r8) * K + cc * 8;
    const f16* Ag1 = Ag0 + (size_t)8 * K;
    const f16* Bg  = BT + (size_t)(n0 + w * 32 + r8) * K + cc * 8;

    int arow0 = m0 + w * 16 + r8;      // MODE 1 rows
    int arow1 = arow0 + 8;

    f32x4 acc[2][4] = {};

    // ---- MODE 1 A-stage: (O0+O1)*linv_h -> swizzled LDS (same layout) ----
    auto stageA1 = [&](int koff, int buf) {
        int hh = koff >> 6;            // BK==HD: one head per k-tile
        const f16* b0 = A + (size_t)hh * SEQ * HD + cc * 8;
        const f16* b1 = b0 + (size_t)NH * SEQ * HD;
        float li0 = 1.0f / (Lp[hh * SEQ + arow0] + Lp[(NH + hh) * SEQ + arow0]);
        float li1 = 1.0f / (Lp[hh * SEQ + arow1] + Lp[(NH + hh) * SEQ + arow1]);
        f16x8 a00 = *(const f16x8*)(b0 + (size_t)arow0 * HD);
        f16x8 a01 = *(const f16x8*)(b1 + (size_t)arow0 * HD);
        f16x8 a10 = *(const f16x8*)(b0 + (size_t)arow1 * HD);
        f16x8 a11 = *(const f16x8*)(b1 + (size_t)arow1 * HD);
        f16x8 r0v, r1v;
#pragma unroll
        for (int j = 0; j < 4; j++) {
            ((h16x2*)&r0v)[j] = __builtin_amdgcn_cvt_pkrtz(
                ((float)a00[2 * j]     + (float)a01[2 * j])     * li0,
                ((float)a00[2 * j + 1] + (float)a01[2 * j + 1]) * li0);
            ((h16x2*)&r1v)[j] = __builtin_amdgcn_cvt_pkrtz(
                ((float)a10[2 * j]     + (float)a11[2 * j])     * li1,
                ((float)a10[2 * j + 1] + (float)a11[2 * j + 1]) * li1);
        }
        *(f16x8*)(&As[buf][w * 1024 + lane * 8])       = r0v;
        *(f16x8*)(&As[buf][w * 1024 + 512 + lane * 8]) = r1v;
    };

    // stage tile 0
    if (MODE == 0) {
        async16(Ag0, &As[0][w * 1024]);
        async16(Ag1, &As[0][w * 1024 + 512]);
    } else {
        stageA1(0, 0);
    }
#pragma unroll
    for (int g = 0; g < 4; g++)
        async16(Bg + (size_t)(8 * g) * K, &Bs[0][w * 2048 + g * 512]);
    __syncthreads();

    int b = 0;
    for (int kt = 64; kt <= K; kt += 64) {
        if (kt < K) {
            if (MODE == 0) {
                async16(Ag0 + kt, &As[b ^ 1][w * 1024]);
                async16(Ag1 + kt, &As[b ^ 1][w * 1024 + 512]);
            } else {
                stageA1(kt, b ^ 1);
            }
#pragma unroll
            for (int g = 0; g < 4; g++)
                async16(Bg + (size_t)(8 * g) * K + kt, &Bs[b ^ 1][w * 2048 + g * 512]);
        }
        f16x8 af[2][2], bf[4][2];
#pragma unroll
        for (int mi = 0; mi < 2; mi++) {
            int row = wm * 32 + mi * 16 + l15;
#pragma unroll
            for (int kh = 0; kh < 2; kh++)
                af[mi][kh] = *(const f16x8*)(&As[b][row * 64 + ((kh * 4 + quad) ^ sw) * 8]);
        }
#pragma unroll
        for (int ni = 0; ni < 4; ni++) {
            int row = wn * 64 + ni * 16 + l15;
#pragma unroll
            for (int kh = 0; kh < 2; kh++)
                bf[ni][kh] = *(const f16x8*)(&Bs[b][row * 64 + ((kh * 4 + quad) ^ sw) * 8]);
        }
#pragma unroll
        for (int mi = 0; mi < 2; mi++)
#pragma unroll
            for (int ni = 0; ni < 4; ni++) {
                acc[mi][ni] = mfma_16x16x32(af[mi][0], bf[ni][0], acc[mi][ni]);
                acc[mi][ni] = mfma_16x16x32(af[mi][1], bf[ni][1], acc[mi][ni]);
            }
        __syncthreads();
        b ^= 1;
    }

    int rb  = m0 + wm * 32 + quad * 4;
    int cbh = n0 + wn * 64;          // 64-aligned: one head per wave column
    if (MODE == 0) {
        if (cbh < (NH + NKV) * HD) {
            bool isQ = cbh < NH * HD;
            f16* dst = isQ ? (Q  + (size_t)(cbh >> 6) * SEQ * HD)
                           : (Kk + (size_t)((cbh - NH * HD) >> 6) * SEQ * HD);
            float scale = isQ ? 0.18033688011112042f : 1.0f;  // (1/8)*log2(e)
            float fr[2];
#pragma unroll
            for (int ni = 0; ni < 2; ni++)
                fr[ni] = __builtin_amdgcn_exp2f(
                    (float)(ni * 16 + l15) * -0.41524101186092029f); // -log2(1e4)/32
#pragma unroll
            for (int mi = 0; mi < 2; mi++)
#pragma unroll
                for (int r = 0; r < 4; r++) {
                    int row = rb + mi * 16 + r;
                    float pv = (float)pos[row];
#pragma unroll
                    for (int ni = 0; ni < 2; ni++) {
                        float sn, cs;
                        __sincosf(pv * fr[ni], &sn, &cs);
                        float x1 = acc[mi][ni][r], x2 = acc[mi][ni + 2][r];
                        int d = ni * 16 + l15;
                        dst[(size_t)row * HD + d]      = (f16)(scale * (x1 * cs - x2 * sn));
                        dst[(size_t)row * HD + d + 32] = (f16)(scale * (x2 * cs + x1 * sn));
                    }
                }
        } else {
            // ---- V^T with mask folded in: VT[c2][s] = v * exp2(mask[s]*log2e).
            const float LOG2E = 1.4426950408889634f;
#pragma unroll
            for (int mi = 0; mi < 2; mi++) {
                float4 mv = *(const float4*)(mask + rb + mi * 16);
                float em[4];
#pragma unroll
                for (int r = 0; r < 4; r++)
                    em[r] = __builtin_amdgcn_exp2f((&mv.x)[r] * LOG2E);
#pragma unroll
                for (int ni = 0; ni < 4; ni++) {
                    int c2 = cbh - (NH + NKV) * HD + ni * 16 + l15;
                    f16x4 v4;
                    ((h16x2*)&v4)[0] = __builtin_amdgcn_cvt_pkrtz(
                        acc[mi][ni][0] * em[0], acc[mi][ni][1] * em[1]);
                    ((h16x2*)&v4)[1] = __builtin_amdgcn_cvt_pkrtz(
                        acc[mi][ni][2] * em[2], acc[mi][ni][3] * em[3]);
                    *(f16x4*)(VT + (size_t)c2 * SEQ + rb + mi * 16) = v4;
                }
            }
        }
    } else {
#pragma unroll
        for (int mi = 0; mi < 2; mi++)
#pragma unroll
            for (int ni = 0; ni < 4; ni++)
#pragma unroll
                for (int r = 0; r < 4; r++)
                    Cf[(size_t)(rb + mi * 16 + r) * N + cbh + ni * 16 + l15] =
                        acc[mi][ni][r];
    }
}

// ---------------- fused flash attention: 4-wave blocks, split-K(2) ----------------
// grid (SEQ/128, NH, 2) = 1024 blocks x 256 threads = 4 blocks/CU (16 waves/CU,
// finer barrier granularity than R12's 8-wave blocks). Wave owns 32 q-rows;
// split z owns 16 of 32 key tiles. Each wave stages 16 K-rows (permuted:
// g(rr)=k_eff) + 16 V-rows. Mask folded into V; l via em-fragment MFMA.
// P stays in registers. LDS = 34 KB. Writes unnormalized O^T + l partials.
__global__ __launch_bounds__(256)
void attn_fused(const f16* __restrict__ Qb, const f16* __restrict__ Kb,
                const f16* __restrict__ VTb, const float* __restrict__ mask,
                f16* __restrict__ Opart, float* __restrict__ Lpart) {
    __shared__ f16 Ks[2][64 * 64];
    __shared__ f16 Vs[2][64 * 64];
    __shared__ f16 Em[SEQ / 2];

    int t = threadIdx.x, w = t >> 6, lane = t & 63, quad = lane >> 4, l15 = lane & 15;
    int h = blockIdx.y, kvh = h >> 2, split = blockIdx.z;
    int qbase = blockIdx.x * 128 + w * 32;
    int key0  = split * (SEQ / 2);
    const f16* Qh = Qb  + (size_t)h   * SEQ * HD;
    const f16* Kh = Kb  + (size_t)kvh * SEQ * HD;
    const f16* Vh = VTb + (size_t)kvh * HD * SEQ;
    int sw = l15 & 7;
    const float LOG2E = 1.4426950408889634f;

    // ---- stage em = exp2(mask*log2e) for this split (once per block) ----
    if (t < 128) {
        int idx = t * 8;
        float4 ma = *(const float4*)(mask + key0 + idx);
        float4 mb = *(const float4*)(mask + key0 + idx + 4);
        f16x8 e;
        ((h16x2*)&e)[0] = __builtin_amdgcn_cvt_pkrtz(
            __builtin_amdgcn_exp2f(ma.x * LOG2E), __builtin_amdgcn_exp2f(ma.y * LOG2E));
        ((h16x2*)&e)[1] = __builtin_amdgcn_cvt_pkrtz(
            __builtin_amdgcn_exp2f(ma.z * LOG2E), __builtin_amdgcn_exp2f(ma.w * LOG2E));
        ((h16x2*)&e)[2] = __builtin_amdgcn_cvt_pkrtz(
            __builtin_amdgcn_exp2f(mb.x * LOG2E), __builtin_amdgcn_exp2f(mb.y * LOG2E));
        ((h16x2*)&e)[3] = __builtin_amdgcn_cvt_pkrtz(
            __builtin_amdgcn_exp2f(mb.z * LOG2E), __builtin_amdgcn_exp2f(mb.w * LOG2E));
        *(f16x8*)(&Em[idx]) = e;
    }

    // ---- staging: each wave stages 16 K-rows (permuted) + 16 V-rows ----
    int r8 = lane >> 3;
    int cc = (lane & 7) ^ r8;
    int gk = 32 * (w >> 1) + 4 * (w & 1) + 8 * (r8 >> 2) + (r8 & 3);
    const f16* kg0 = Kh + (size_t)(key0 + gk) * HD + cc * 8;
    const f16* kg1 = kg0 + (size_t)16 * HD;
    const f16* vg0 = Vh + (size_t)(w * 16 + r8) * SEQ + key0 + cc * 8;
    const f16* vg1 = vg0 + 8 * SEQ;
    int lr0 = (w * 16) * 64, lr1 = (w * 16 + 8) * 64;

    async16(kg0, &Ks[0][lr0]);
    async16(kg1, &Ks[0][lr1]);
    async16(vg0, &Vs[0][lr0]);
    async16(vg1, &Vs[0][lr1]);

    // ---- Q fragments (persistent): B-operand of S^T, n = q ----
    f16x8 bq[2][2];
#pragma unroll
    for (int qg = 0; qg < 2; qg++)
#pragma unroll
        for (int ks = 0; ks < 2; ks++)
            bq[qg][ks] = *(const f16x8*)(Qh + (size_t)(qbase + qg * 16 + l15) * HD
                                            + ks * 32 + quad * 8);

    f32x4 o[4][2] = {};          // O^T: [d-tile][q-group]
    f32x4 ol[2]   = {};          // l accumulator (all rows identical)

    int c0 = (quad ^ sw) * 8, c1 = ((4 | quad) ^ sw) * 8;

    __syncthreads();
    int b = 0;

    for (int ktl = 0; ktl < SEQ / 128; ktl++) {
        if (ktl + 1 < SEQ / 128) {
            kg0 += 64 * HD; kg1 += 64 * HD; vg0 += 64; vg1 += 64;
            async16(kg0, &Ks[b ^ 1][lr0]);
            async16(kg1, &Ks[b ^ 1][lr1]);
            async16(vg0, &Vs[b ^ 1][lr0]);
            async16(vg1, &Vs[b ^ 1][lr1]);
        }
        const f16* Kb_ = &Ks[b][0];
        const f16* Vb_ = &Vs[b][0];

        // ---- S^T = K @ Q^T (keys in permuted order) ----
        f32x4 st[4][2] = {};
#pragma unroll
        for (int ni = 0; ni < 4; ni++) {
            const f16* kr = Kb_ + (ni * 16 + l15) * 64;
            f16x8 ak0 = *(const f16x8*)(kr + c0);
            f16x8 ak1 = *(const f16x8*)(kr + c1);
#pragma unroll
            for (int qg = 0; qg < 2; qg++) {
                st[ni][qg] = mfma_16x16x32(ak0, bq[qg][0], st[ni][qg]);
                st[ni][qg] = mfma_16x16x32(ak1, bq[qg][1], st[ni][qg]);
            }
        }
        // ---- p = exp2(s) (mask lives in V); pack via cvt_pkrtz ----
        f16x8 pb[2][2];   // [qg][ks]
#pragma unroll
        for (int ni = 0; ni < 4; ni++)
#pragma unroll
            for (int qg = 0; qg < 2; qg++) {
                h16x2 lo = __builtin_amdgcn_cvt_pkrtz(
                    __builtin_amdgcn_exp2f(st[ni][qg][0]),
                    __builtin_amdgcn_exp2f(st[ni][qg][1]));
                h16x2 hi = __builtin_amdgcn_cvt_pkrtz(
                    __builtin_amdgcn_exp2f(st[ni][qg][2]),
                    __builtin_amdgcn_exp2f(st[ni][qg][3]));
                ((h16x2*)&pb[qg][ni >> 1])[(ni & 1) * 2]     = lo;
                ((h16x2*)&pb[qg][ni >> 1])[(ni & 1) * 2 + 1] = hi;
            }
        // ---- l += em-row @ P (MFMA; every output row = l[q]) ----
        f16x8 em0 = *(const f16x8*)(&Em[ktl * 64 + quad * 8]);
        f16x8 em1 = *(const f16x8*)(&Em[ktl * 64 + 32 + quad * 8]);
#pragma unroll
        for (int qg = 0; qg < 2; qg++) {
            ol[qg] = mfma_16x16x32(em0, pb[qg][0], ol[qg]);
            ol[qg] = mfma_16x16x32(em1, pb[qg][1], ol[qg]);
        }
        // ---- O^T += V^T @ P ----
#pragma unroll
        for (int dt = 0; dt < 4; dt++) {
            const f16* vr = Vb_ + (dt * 16 + l15) * 64;
            f16x8 av0 = *(const f16x8*)(vr + c0);
            f16x8 av1 = *(const f16x8*)(vr + c1);
#pragma unroll
            for (int qg = 0; qg < 2; qg++) {
                o[dt][qg] = mfma_16x16x32(av0, pb[qg][0], o[dt][qg]);
                o[dt][qg] = mfma_16x16x32(av1, pb[qg][1], o[dt][qg]);
            }
        }
        __syncthreads();
        b ^= 1;
    }

    // ---- l partial: all lanes hold l[q = qg*16+l15]; quad 0 writes ----
    if (quad == 0) {
#pragma unroll
        for (int qg = 0; qg < 2; qg++)
            Lpart[((size_t)split * NH + h) * SEQ + qbase + qg * 16 + l15] =
                ol[qg][0];
    }
    // ---- unnormalized O^T partial: lane d = dt*16+quad*4+r, q = qg*16+l15 ----
    f16* Op = Opart + ((size_t)split * NH + h) * SEQ * HD;
#pragma unroll
    for (int dt = 0; dt < 4; dt++)
#pragma unroll
        for (int qg = 0; qg < 2; qg++) {
            f16x4 v4;
            ((h16x2*)&v4)[0] = __builtin_amdgcn_cvt_pkrtz(o[dt][qg][0], o[dt][qg][1]);
            ((h16x2*)&v4)[1] = __builtin_amdgcn_cvt_pkrtz(o[dt][qg][2], o[dt][qg][3]);
            *(f16x4*)(Op + (size_t)(qbase + qg * 16 + l15) * HD
                         + dt * 16 + quad * 4) = v4;
        }
}

// ---------------- launch ----------------
extern "C" void kernel_launch(void* const* d_in, const int* in_sizes, int n_in,
                              void* d_out, int out_size, void* d_ws, size_t ws_size,
                              hipStream_t stream) {
    const float* x    = (const float*)d_in[0];
    const float* mask = (const float*)d_in[1];
    const int*   pos  = (const int*)  d_in[2];
    const float* wq   = (const float*)d_in[3];
    const float* wk   = (const float*)d_in[4];
    const float* wv   = (const float*)d_in[5];
    const float* wo   = (const float*)d_in[6];
    float* out = (float*)d_out;

    char* ws = (char*)d_ws;
    // phase 1-2: xb [0,8M), Wcat [8,20M), woT [20,28M), Qb [28,36M),
    //            Kb [36,38M), VTb [38,40M)
    // phase 3:   Opart [0,16M) (xb/Wcat dead), Lpart [16,16.5M)
    // phase 4:   O-proj reads Opart+Lpart directly (combine fused), woT live
    f16*   xb    = (f16*)(ws);
    f16*   Wcat  = (f16*)(ws + ((size_t)8  << 20));
    f16*   woT   = (f16*)(ws + ((size_t)20 << 20));
    f16*   Qb    = (f16*)(ws + ((size_t)28 << 20));
    f16*   Kb    = (f16*)(ws + ((size_t)36 << 20));
    f16*   VTb   = (f16*)(ws + ((size_t)38 << 20));
    f16*   Opart = (f16*)(ws);
    float* Lpart = (float*)(ws + ((size_t)16 << 20));

    prep_all<<<dim3(64, 64, 5), dim3(32, 8), 0, stream>>>(
        x, wq, wk, wv, wo, xb, Wcat, woT);

    // fused Q/K/V projection + RoPE + mask-folded V: C[2048,3072] = xb @ Wcat^T
    gemm_bt<0><<<dim3(3072 / 128, 2048 / 64), 256, 0, stream>>>(
        xb, Wcat, nullptr, Qb, Kb, VTb, pos, mask, nullptr, 3072, 2048);

    attn_fused<<<dim3(SEQ / 128, NH, 2), 256, 0, stream>>>(
        Qb, Kb, VTb, mask, Opart, Lpart);

    // out = ((O0+O1)/l) @ wo  -- combine fused into A-staging, fp32 direct
    gemm_bt<1><<<dim3(2048 / 128, 2048 / 64), 256, 0, stream>>>(
        Opart, woT, out, nullptr, nullptr, nullptr, nullptr, nullptr, Lpart,
        2048, 2048);
}